// Round 3
// baseline (417.790 us; speedup 1.0000x reference)
//
#include <hip/hip_runtime.h>
#include <hip/hip_bf16.h>

#define LOG2E 1.44269504088896340736f

typedef __attribute__((ext_vector_type(8))) short short8_t;   // 8 bf16 in 4 VGPRs
typedef __attribute__((ext_vector_type(4))) float f32x4_t;
typedef __attribute__((ext_vector_type(4))) unsigned short us4_t;

__device__ __forceinline__ unsigned short f2bf(float f) {
  unsigned u = __builtin_bit_cast(unsigned, f);
  return (unsigned short)((u + 0x7fffu + ((u >> 16) & 1u)) >> 16);
}

__device__ __forceinline__ void gload_lds16(const unsigned short* g, unsigned short* l) {
  __builtin_amdgcn_global_load_lds(
      (const __attribute__((address_space(1))) void*)(g),
      (__attribute__((address_space(3))) void*)(l), 16, 0, 0);
}

// ---------------------------------------------------------------- convert f32 -> bf16
__global__ __launch_bounds__(256) void cvt3(
    const float* __restrict__ x, const float* __restrict__ wq, const float* __restrict__ wo,
    unsigned short* __restrict__ xb, unsigned short* __restrict__ wqb,
    unsigned short* __restrict__ wob)
{
  const int n1 = 4096 * 1024 / 4, n2 = 3072 * 1024 / 4, n3 = 1024 * 1024 / 4;
  const int total = n1 + n2 + n3;
  for (int t = blockIdx.x * blockDim.x + threadIdx.x; t < total; t += gridDim.x * blockDim.x) {
    const float* s; unsigned short* d; int off;
    if (t < n1)            { s = x;  d = xb;  off = t * 4; }
    else if (t < n1 + n2)  { s = wq; d = wqb; off = (t - n1) * 4; }
    else                   { s = wo; d = wob; off = (t - n1 - n2) * 4; }
    f32x4_t v = *(const f32x4_t*)(s + off);
    us4_t o = { f2bf(v[0]), f2bf(v[1]), f2bf(v[2]), f2bf(v[3]) };
    *(us4_t*)(d + off) = o;
  }
}

// ---------------------------------------------------------------- 128x128 bf16 GEMM, C = A * Bw^T + bias
// A: [M][K] bf16 row-major, Bw: [N][K] bf16 row-major.
// MODE 0: scatter-epilogue to Q [BH][L][64], K [BH][L][64], Vt [BH][64][L] (bf16)
// MODE 1: f32 output Cf[M][N]
template<int MODE>
__global__ __launch_bounds__(256) void gemm_bt(
    const unsigned short* __restrict__ A, const unsigned short* __restrict__ Bw,
    const float* __restrict__ bias, float* __restrict__ Cf,
    unsigned short* __restrict__ Qp, unsigned short* __restrict__ Kp,
    unsigned short* __restrict__ Vtp, int M, int N, int K)
{
  __shared__ alignas(16) unsigned short lA[128 * 32];
  __shared__ alignas(16) unsigned short lB[128 * 32];
  const int tid = threadIdx.x, lane = tid & 63, w = tid >> 6;
  const int lo = lane & 15, hi = lane >> 4;
  const int bm = blockIdx.y * 128, bn = blockIdx.x * 128;
  const int wm = (w >> 1) * 64, wn = (w & 1) * 64;

  const f32x4_t zero = {0.f, 0.f, 0.f, 0.f};
  f32x4_t acc[4][4];
#pragma unroll
  for (int i = 0; i < 4; ++i)
#pragma unroll
    for (int j = 0; j < 4; ++j) acc[i][j] = zero;

  // staging assignment: wave-uniform LDS base + lane*16B (global_load_lds constraint)
  const unsigned short* gA[2]; const unsigned short* gB[2];
  unsigned short* lAp[2]; unsigned short* lBp[2];
#pragma unroll
  for (int i = 0; i < 2; ++i) {
    int offb = (i * 4 + w) * 1024;        // wave-uniform byte base in 8KB tile
    int off  = offb + lane * 16;          // this lane's dest byte
    int row  = off >> 6;                  // 64B per row (32 bf16)
    int ke   = (off & 63) >> 1;
    gA[i]  = &A [(size_t)(bm + row) * K + ke];
    gB[i]  = &Bw[(size_t)(bn + row) * K + ke];
    lAp[i] = &lA[offb >> 1];
    lBp[i] = &lB[offb >> 1];
  }

  for (int k0 = 0; k0 < K; k0 += 32) {
#pragma unroll
    for (int i = 0; i < 2; ++i) {
      gload_lds16(gA[i] + k0, lAp[i]);
      gload_lds16(gB[i] + k0, lBp[i]);
    }
    __syncthreads();                       // drains vmcnt before any ds_read
    short8_t af[4], bb[4];
#pragma unroll
    for (int i = 0; i < 4; ++i) af[i] = *(const short8_t*)&lA[(wm + i * 16 + lo) * 32 + hi * 8];
#pragma unroll
    for (int j = 0; j < 4; ++j) bb[j] = *(const short8_t*)&lB[(wn + j * 16 + lo) * 32 + hi * 8];
#pragma unroll
    for (int i = 0; i < 4; ++i)
#pragma unroll
      for (int j = 0; j < 4; ++j)
        acc[i][j] = __builtin_amdgcn_mfma_f32_16x16x32_bf16(af[i], bb[j], acc[i][j], 0, 0, 0);
    __syncthreads();
  }

  // epilogue: C/D layout col=lane&15, row=(lane>>4)*4+reg  [verified m89]
#pragma unroll
  for (int i = 0; i < 4; ++i) {
#pragma unroll
    for (int j = 0; j < 4; ++j) {
      int col = bn + wn + j * 16 + lo;
      float bv = bias[col];
#pragma unroll
      for (int r = 0; r < 4; ++r) {
        int row = bm + wm + i * 16 + hi * 4 + r;
        float v = acc[i][j][r] + bv;
        if (MODE == 1) {
          Cf[(size_t)row * N + col] = v;
        } else {
          unsigned short hv = f2bf(v);
          int sec = col >> 10, h = (col >> 6) & 15, d = col & 63;
          int b = row >> 11, ll = row & 2047;
          int bh = b * 16 + h;
          if (sec == 0)      Qp [((size_t)bh * 2048 + ll) * 64 + d] = hv;
          else if (sec == 1) Kp [((size_t)bh * 2048 + ll) * 64 + d] = hv;
          else               Vtp[((size_t)bh * 64 + d) * 2048 + ll] = hv;
        }
      }
    }
  }
}

// ---------------------------------------------------------------- causal flash attention
// Q,K: [BH][2048][64] bf16; Vt: [BH][64][2048] bf16; AO: [B][L][1024] bf16
// 4 waves/block; wave w owns 16 q-rows; wave-synchronous (no block barriers).
__global__ __launch_bounds__(256) void attn(
    const unsigned short* __restrict__ Q, const unsigned short* __restrict__ K,
    const unsigned short* __restrict__ V, unsigned short* __restrict__ AO)
{
  const int tid = threadIdx.x, lane = tid & 63, w = tid >> 6;
  const int lo = lane & 15, hi = lane >> 4;
  const int qt = blockIdx.x, bh = blockIdx.y;
  const int qbase = qt * 64 + w * 16;
  const unsigned short* Qb = Q + (size_t)bh * 2048 * 64;
  const unsigned short* Kb = K + (size_t)bh * 2048 * 64;
  const unsigned short* Vb = V + (size_t)bh * 64 * 2048;

  __shared__ alignas(16) unsigned short pl[4][16 * 40];  // per-wave P tile, stride 40 (+pad)
  unsigned short* myP = &pl[w][0];

  // Q fragments (held in registers for the whole kernel)
  short8_t qf0 = *(const short8_t*)&Qb[(qbase + lo) * 64 + hi * 8];
  short8_t qf1 = *(const short8_t*)&Qb[(qbase + lo) * 64 + 32 + hi * 8];

  const f32x4_t zero = {0.f, 0.f, 0.f, 0.f};
  f32x4_t o[4] = {zero, zero, zero, zero};
  float m[4] = {-INFINITY, -INFINITY, -INFINITY, -INFINITY};
  float l[4] = {0.f, 0.f, 0.f, 0.f};
  const float SC = 0.125f * LOG2E;   // 1/sqrt(64) * log2(e): softmax in exp2 domain

  const int nk = qbase + 16;         // keys needed: k <= qbase+15 (causal)
  for (int kb = 0; kb < nk; kb += 32) {
    f32x4_t s0 = zero, s1 = zero;
    short8_t k00 = *(const short8_t*)&Kb[(kb + lo) * 64 + hi * 8];
    short8_t k01 = *(const short8_t*)&Kb[(kb + lo) * 64 + 32 + hi * 8];
    short8_t k10 = *(const short8_t*)&Kb[(kb + 16 + lo) * 64 + hi * 8];
    short8_t k11 = *(const short8_t*)&Kb[(kb + 16 + lo) * 64 + 32 + hi * 8];
    s0 = __builtin_amdgcn_mfma_f32_16x16x32_bf16(qf0, k00, s0, 0, 0, 0);
    s0 = __builtin_amdgcn_mfma_f32_16x16x32_bf16(qf1, k01, s0, 0, 0, 0);
    s1 = __builtin_amdgcn_mfma_f32_16x16x32_bf16(qf0, k10, s1, 0, 0, 0);
    s1 = __builtin_amdgcn_mfma_f32_16x16x32_bf16(qf1, k11, s1, 0, 0, 0);
    s0 *= SC; s1 *= SC;

    const bool needmask = (kb + 31 > qbase);
#pragma unroll
    for (int r = 0; r < 4; ++r) {
      int q = qbase + hi * 4 + r;
      float a0 = s0[r], a1 = s1[r];
      if (needmask) {
        if (kb + lo > q)      a0 = -INFINITY;
        if (kb + 16 + lo > q) a1 = -INFINITY;
      }
      float t = fmaxf(a0, a1);
      t = fmaxf(t, __shfl_xor(t, 1));
      t = fmaxf(t, __shfl_xor(t, 2));
      t = fmaxf(t, __shfl_xor(t, 4));
      t = fmaxf(t, __shfl_xor(t, 8));
      float mn = fmaxf(m[r], t);
      float f = exp2f(m[r] - mn);
      m[r] = mn;
      float e0 = exp2f(a0 - mn);
      float e1 = exp2f(a1 - mn);
      float rs = e0 + e1;
      rs += __shfl_xor(rs, 1);
      rs += __shfl_xor(rs, 2);
      rs += __shfl_xor(rs, 4);
      rs += __shfl_xor(rs, 8);
      l[r] = l[r] * f + rs;
#pragma unroll
      for (int j = 0; j < 4; ++j) o[j][r] *= f;
      myP[(hi * 4 + r) * 40 + lo]      = f2bf(e0);
      myP[(hi * 4 + r) * 40 + 16 + lo] = f2bf(e1);
    }
    // re-layout P (D-layout -> A-fragment) via per-wave LDS; wave-synchronous
    short8_t pf = *(const short8_t*)&myP[lo * 40 + hi * 8];
#pragma unroll
    for (int j = 0; j < 4; ++j) {
      short8_t vf = *(const short8_t*)&Vb[(size_t)(j * 16 + lo) * 2048 + kb + hi * 8];
      o[j] = __builtin_amdgcn_mfma_f32_16x16x32_bf16(pf, vf, o[j], 0, 0, 0);
    }
  }

  const int b = bh >> 4, h = bh & 15;
#pragma unroll
  for (int r = 0; r < 4; ++r) {
    float inv = 1.0f / l[r];
    int qrow = qbase + hi * 4 + r;
    size_t base = ((size_t)b * 2048 + qrow) * 1024 + h * 64;
#pragma unroll
    for (int j = 0; j < 4; ++j)
      AO[base + j * 16 + lo] = f2bf(o[j][r] * inv);
  }
}

// ---------------------------------------------------------------- launch
extern "C" void kernel_launch(void* const* d_in, const int* in_sizes, int n_in,
                              void* d_out, int out_size, void* d_ws, size_t ws_size,
                              hipStream_t stream)
{
  (void)in_sizes; (void)n_in; (void)out_size; (void)ws_size;
  const float* x    = (const float*)d_in[0];
  // d_in[1] = mask (causal, hardcoded)
  const float* Wqkv = (const float*)d_in[2];
  const float* bqkv = (const float*)d_in[3];
  const float* Wout = (const float*)d_in[4];
  const float* bout = (const float*)d_in[5];

  unsigned short* ws  = (unsigned short*)d_ws;
  unsigned short* xb  = ws;                       // 4096*1024
  unsigned short* wqb = xb  + 4096 * 1024;        // 3072*1024
  unsigned short* wob = wqb + 3072 * 1024;        // 1024*1024
  unsigned short* Qp  = wob + 1024 * 1024;        // 32*2048*64
  unsigned short* Kp  = Qp  + 32 * 2048 * 64;
  unsigned short* Vtp = Kp  + 32 * 2048 * 64;
  unsigned short* AO  = Vtp + 32 * 2048 * 64;     // 4096*1024

  cvt3<<<dim3(2048), dim3(256), 0, stream>>>(x, Wqkv, Wout, xb, wqb, wob);
  gemm_bt<0><<<dim3(24, 32), dim3(256), 0, stream>>>(
      xb, wqb, bqkv, nullptr, Qp, Kp, Vtp, 4096, 3072, 1024);
  attn<<<dim3(32, 32), dim3(256), 0, stream>>>(Qp, Kp, Vtp, AO);
  gemm_bt<1><<<dim3(8, 32), dim3(256), 0, stream>>>(
      AO, wob, bout, (float*)d_out, nullptr, nullptr, nullptr, 4096, 1024, 1024);
}

// Round 4
// 318.276 us; speedup vs baseline: 1.3127x; 1.3127x over previous
//
#include <hip/hip_runtime.h>
#include <hip/hip_bf16.h>

#define LOG2E 1.44269504088896340736f

typedef __attribute__((ext_vector_type(8))) short short8_t;   // 8 bf16 in 4 VGPRs
typedef __attribute__((ext_vector_type(4))) float f32x4_t;
typedef __attribute__((ext_vector_type(4))) unsigned short us4_t;

__device__ __forceinline__ unsigned short f2bf(float f) {
  unsigned u = __builtin_bit_cast(unsigned, f);
  return (unsigned short)((u + 0x7fffu + ((u >> 16) & 1u)) >> 16);
}

__device__ __forceinline__ void gload_lds16(const unsigned short* g, unsigned short* l) {
  __builtin_amdgcn_global_load_lds(
      (const __attribute__((address_space(1))) void*)(g),
      (__attribute__((address_space(3))) void*)(l), 16, 0, 0);
}

// ---------------------------------------------------------------- convert f32 -> bf16
__global__ __launch_bounds__(256) void cvt3(
    const float* __restrict__ x, const float* __restrict__ wq, const float* __restrict__ wo,
    unsigned short* __restrict__ xb, unsigned short* __restrict__ wqb,
    unsigned short* __restrict__ wob)
{
  const int n1 = 4096 * 1024 / 4, n2 = 3072 * 1024 / 4, n3 = 1024 * 1024 / 4;
  const int total = n1 + n2 + n3;
  for (int t = blockIdx.x * blockDim.x + threadIdx.x; t < total; t += gridDim.x * blockDim.x) {
    const float* s; unsigned short* d; int off;
    if (t < n1)            { s = x;  d = xb;  off = t * 4; }
    else if (t < n1 + n2)  { s = wq; d = wqb; off = (t - n1) * 4; }
    else                   { s = wo; d = wob; off = (t - n1 - n2) * 4; }
    f32x4_t v = *(const f32x4_t*)(s + off);
    us4_t o = { f2bf(v[0]), f2bf(v[1]), f2bf(v[2]), f2bf(v[3]) };
    *(us4_t*)(d + off) = o;
  }
}

// ---------------------------------------------------------------- 128x128 bf16 GEMM, C = A * Bw^T + bias
template<int MODE>
__global__ __launch_bounds__(256) void gemm_bt(
    const unsigned short* __restrict__ A, const unsigned short* __restrict__ Bw,
    const float* __restrict__ bias, float* __restrict__ Cf,
    unsigned short* __restrict__ Qp, unsigned short* __restrict__ Kp,
    unsigned short* __restrict__ Vtp, int M, int N, int K)
{
  __shared__ alignas(16) unsigned short lA[128 * 32];
  __shared__ alignas(16) unsigned short lB[128 * 32];
  const int tid = threadIdx.x, lane = tid & 63, w = tid >> 6;
  const int lo = lane & 15, hi = lane >> 4;
  const int bm = blockIdx.y * 128, bn = blockIdx.x * 128;
  const int wm = (w >> 1) * 64, wn = (w & 1) * 64;

  const f32x4_t zero = {0.f, 0.f, 0.f, 0.f};
  f32x4_t acc[4][4];
#pragma unroll
  for (int i = 0; i < 4; ++i)
#pragma unroll
    for (int j = 0; j < 4; ++j) acc[i][j] = zero;

  const unsigned short* gA[2]; const unsigned short* gB[2];
  unsigned short* lAp[2]; unsigned short* lBp[2];
#pragma unroll
  for (int i = 0; i < 2; ++i) {
    int offb = (i * 4 + w) * 1024;
    int off  = offb + lane * 16;
    int row  = off >> 6;
    int ke   = (off & 63) >> 1;
    gA[i]  = &A [(size_t)(bm + row) * K + ke];
    gB[i]  = &Bw[(size_t)(bn + row) * K + ke];
    lAp[i] = &lA[offb >> 1];
    lBp[i] = &lB[offb >> 1];
  }

  for (int k0 = 0; k0 < K; k0 += 32) {
#pragma unroll
    for (int i = 0; i < 2; ++i) {
      gload_lds16(gA[i] + k0, lAp[i]);
      gload_lds16(gB[i] + k0, lBp[i]);
    }
    __syncthreads();
    short8_t af[4], bb[4];
#pragma unroll
    for (int i = 0; i < 4; ++i) af[i] = *(const short8_t*)&lA[(wm + i * 16 + lo) * 32 + hi * 8];
#pragma unroll
    for (int j = 0; j < 4; ++j) bb[j] = *(const short8_t*)&lB[(wn + j * 16 + lo) * 32 + hi * 8];
#pragma unroll
    for (int i = 0; i < 4; ++i)
#pragma unroll
      for (int j = 0; j < 4; ++j)
        acc[i][j] = __builtin_amdgcn_mfma_f32_16x16x32_bf16(af[i], bb[j], acc[i][j], 0, 0, 0);
    __syncthreads();
  }

#pragma unroll
  for (int i = 0; i < 4; ++i) {
#pragma unroll
    for (int j = 0; j < 4; ++j) {
      int col = bn + wn + j * 16 + lo;
      float bv = bias[col];
#pragma unroll
      for (int r = 0; r < 4; ++r) {
        int row = bm + wm + i * 16 + hi * 4 + r;
        float v = acc[i][j][r] + bv;
        if (MODE == 1) {
          Cf[(size_t)row * N + col] = v;
        } else {
          unsigned short hv = f2bf(v);
          int sec = col >> 10, h = (col >> 6) & 15, d = col & 63;
          int b = row >> 11, ll = row & 2047;
          int bh = b * 16 + h;
          if (sec == 0)      Qp [((size_t)bh * 2048 + ll) * 64 + d] = hv;
          else if (sec == 1) Kp [((size_t)bh * 2048 + ll) * 64 + d] = hv;
          else               Vtp[((size_t)bh * 64 + d) * 2048 + ll] = hv;
        }
      }
    }
  }
}

// ---------------------------------------------------------------- causal flash attention v2
// Q,K: [BH][2048][64] bf16; Vt: [BH][64][2048] bf16; AO: [B][L][1024] bf16
// 4 waves/block, wave owns 16 q-rows, KVBLK=64, software-pipelined, LPT order.
__global__ __launch_bounds__(256) void attn(
    const unsigned short* __restrict__ Q, const unsigned short* __restrict__ K,
    const unsigned short* __restrict__ V, unsigned short* __restrict__ AO)
{
  const int tid = threadIdx.x, lane = tid & 63, w = tid >> 6;
  const int lo = lane & 15, hi = lane >> 4;
  // LPT: biggest q-tiles dispatch first (y is the slow grid dim)
  const int qt = 31 - blockIdx.y;
  const int bh = blockIdx.x;
  const int qbase = qt * 64 + w * 16;
  const unsigned short* Qb = Q + (size_t)bh * 2048 * 64;
  const unsigned short* Kb = K + (size_t)bh * 2048 * 64;
  const unsigned short* Vb = V + (size_t)bh * 64 * 2048;

  __shared__ alignas(16) unsigned short pl[4][16 * 72];  // per-wave P tile, stride 72
  unsigned short* myP = &pl[w][0];

  short8_t qf0 = *(const short8_t*)&Qb[(qbase + lo) * 64 + hi * 8];
  short8_t qf1 = *(const short8_t*)&Qb[(qbase + lo) * 64 + 32 + hi * 8];

  const f32x4_t zero = {0.f, 0.f, 0.f, 0.f};
  f32x4_t o[4] = {zero, zero, zero, zero};
  float m[4] = {-INFINITY, -INFINITY, -INFINITY, -INFINITY};
  float l[4] = {0.f, 0.f, 0.f, 0.f};
  const float SC = 0.125f * LOG2E;   // 1/sqrt(64) * log2(e): exp2 domain

  const int nk = qbase + 16;         // keys needed: k <= qbase+15 (causal)
  const unsigned short* kfb = &Kb[(size_t)lo * 64 + hi * 8];

  // prologue: preload K tile for kb=0 (rows s*16+lo, all <= 63 < 2048)
  short8_t kf[8];
#pragma unroll
  for (int s = 0; s < 4; ++s) {
    kf[s * 2 + 0] = *(const short8_t*)&kfb[(s * 16) * 64];
    kf[s * 2 + 1] = *(const short8_t*)&kfb[(s * 16) * 64 + 32];
  }

  for (int kb = 0; kb < nk; kb += 64) {
    // V loads issued early: latency hides under QK + softmax
    short8_t vf[8];
#pragma unroll
    for (int j = 0; j < 4; ++j) {
      vf[j * 2 + 0] = *(const short8_t*)&Vb[(size_t)(j * 16 + lo) * 2048 + kb + hi * 8];
      vf[j * 2 + 1] = *(const short8_t*)&Vb[(size_t)(j * 16 + lo) * 2048 + kb + 32 + hi * 8];
    }

    // QK^T: S[16q][64k], 8 MFMA
    f32x4_t s4[4] = {zero, zero, zero, zero};
    __builtin_amdgcn_s_setprio(1);
#pragma unroll
    for (int s = 0; s < 4; ++s) {
      s4[s] = __builtin_amdgcn_mfma_f32_16x16x32_bf16(qf0, kf[s * 2 + 0], s4[s], 0, 0, 0);
      s4[s] = __builtin_amdgcn_mfma_f32_16x16x32_bf16(qf1, kf[s * 2 + 1], s4[s], 0, 0, 0);
    }
    __builtin_amdgcn_s_setprio(0);

    // prefetch next K tile (kf regs dead after QK); hides under softmax+PV.
    // bounds: kb+64 multiple of 64 and < nk <= 2048 -> rows <= kb+127 <= 2047.
    if (kb + 64 < nk) {
      const unsigned short* kn = kfb + (size_t)(kb + 64) * 64;
#pragma unroll
      for (int s = 0; s < 4; ++s) {
        kf[s * 2 + 0] = *(const short8_t*)&kn[(s * 16) * 64];
        kf[s * 2 + 1] = *(const short8_t*)&kn[(s * 16) * 64 + 32];
      }
    }

#pragma unroll
    for (int s = 0; s < 4; ++s) s4[s] *= SC;

    const bool needmask = (kb + 64 > qbase);
#pragma unroll
    for (int r = 0; r < 4; ++r) {
      int q = qbase + hi * 4 + r;
      float a0 = s4[0][r], a1 = s4[1][r], a2 = s4[2][r], a3 = s4[3][r];
      if (needmask) {
        if (kb + lo > q)      a0 = -INFINITY;
        if (kb + 16 + lo > q) a1 = -INFINITY;
        if (kb + 32 + lo > q) a2 = -INFINITY;
        if (kb + 48 + lo > q) a3 = -INFINITY;
      }
      // merged row-max over 64 keys: 3 fmax in-reg + 4 shfl levels (within lo-group)
      float t = fmaxf(fmaxf(a0, a1), fmaxf(a2, a3));
      t = fmaxf(t, __shfl_xor(t, 1));
      t = fmaxf(t, __shfl_xor(t, 2));
      t = fmaxf(t, __shfl_xor(t, 4));
      t = fmaxf(t, __shfl_xor(t, 8));
      float mn = fmaxf(m[r], t);
      float f = __builtin_amdgcn_exp2f(m[r] - mn);
      m[r] = mn;
      float e0 = __builtin_amdgcn_exp2f(a0 - mn);
      float e1 = __builtin_amdgcn_exp2f(a1 - mn);
      float e2 = __builtin_amdgcn_exp2f(a2 - mn);
      float e3 = __builtin_amdgcn_exp2f(a3 - mn);
      float rs = (e0 + e1) + (e2 + e3);
      rs += __shfl_xor(rs, 1);
      rs += __shfl_xor(rs, 2);
      rs += __shfl_xor(rs, 4);
      rs += __shfl_xor(rs, 8);
      l[r] = l[r] * f + rs;
#pragma unroll
      for (int j = 0; j < 4; ++j) o[j][r] *= f;
      int prow = (hi * 4 + r) * 72;
      myP[prow + lo]      = f2bf(e0);
      myP[prow + 16 + lo] = f2bf(e1);
      myP[prow + 32 + lo] = f2bf(e2);
      myP[prow + 48 + lo] = f2bf(e3);
    }

    // P re-layout (D-layout -> A-frag) via per-wave LDS; wave-synchronous
    short8_t pf0 = *(const short8_t*)&myP[lo * 72 + hi * 8];
    short8_t pf1 = *(const short8_t*)&myP[lo * 72 + 32 + hi * 8];
    __builtin_amdgcn_s_setprio(1);
#pragma unroll
    for (int j = 0; j < 4; ++j) {
      o[j] = __builtin_amdgcn_mfma_f32_16x16x32_bf16(pf0, vf[j * 2 + 0], o[j], 0, 0, 0);
      o[j] = __builtin_amdgcn_mfma_f32_16x16x32_bf16(pf1, vf[j * 2 + 1], o[j], 0, 0, 0);
    }
    __builtin_amdgcn_s_setprio(0);
  }

  const int b = bh >> 4, h = bh & 15;
#pragma unroll
  for (int r = 0; r < 4; ++r) {
    float inv = 1.0f / l[r];
    int qrow = qbase + hi * 4 + r;
    size_t base = ((size_t)b * 2048 + qrow) * 1024 + h * 64;
#pragma unroll
    for (int j = 0; j < 4; ++j)
      AO[base + j * 16 + lo] = f2bf(o[j][r] * inv);
  }
}

// ---------------------------------------------------------------- launch
extern "C" void kernel_launch(void* const* d_in, const int* in_sizes, int n_in,
                              void* d_out, int out_size, void* d_ws, size_t ws_size,
                              hipStream_t stream)
{
  (void)in_sizes; (void)n_in; (void)out_size; (void)ws_size;
  const float* x    = (const float*)d_in[0];
  const float* Wqkv = (const float*)d_in[2];
  const float* bqkv = (const float*)d_in[3];
  const float* Wout = (const float*)d_in[4];
  const float* bout = (const float*)d_in[5];

  unsigned short* ws  = (unsigned short*)d_ws;
  unsigned short* xb  = ws;                       // 4096*1024
  unsigned short* wqb = xb  + 4096 * 1024;        // 3072*1024
  unsigned short* wob = wqb + 3072 * 1024;        // 1024*1024
  unsigned short* Qp  = wob + 1024 * 1024;        // 32*2048*64
  unsigned short* Kp  = Qp  + 32 * 2048 * 64;
  unsigned short* Vtp = Kp  + 32 * 2048 * 64;
  unsigned short* AO  = Vtp + 32 * 2048 * 64;     // 4096*1024

  cvt3<<<dim3(2048), dim3(256), 0, stream>>>(x, Wqkv, Wout, xb, wqb, wob);
  gemm_bt<0><<<dim3(24, 32), dim3(256), 0, stream>>>(
      xb, wqb, bqkv, nullptr, Qp, Kp, Vtp, 4096, 3072, 1024);
  attn<<<dim3(32, 32), dim3(256), 0, stream>>>(Qp, Kp, Vtp, AO);
  gemm_bt<1><<<dim3(8, 32), dim3(256), 0, stream>>>(
      AO, wob, bout, (float*)d_out, nullptr, nullptr, nullptr, 4096, 1024, 1024);
}

// Round 5
// 317.892 us; speedup vs baseline: 1.3142x; 1.0012x over previous
//
#include <hip/hip_runtime.h>
#include <hip/hip_bf16.h>

#define LOG2E 1.44269504088896340736f

typedef __attribute__((ext_vector_type(8))) short short8_t;   // 8 bf16 in 4 VGPRs
typedef __attribute__((ext_vector_type(4))) float f32x4_t;
typedef __attribute__((ext_vector_type(4))) unsigned short us4_t;

__device__ __forceinline__ unsigned short f2bf(float f) {
  unsigned u = __builtin_bit_cast(unsigned, f);
  return (unsigned short)((u + 0x7fffu + ((u >> 16) & 1u)) >> 16);
}

__device__ __forceinline__ void gload_lds16(const unsigned short* g, unsigned short* l) {
  __builtin_amdgcn_global_load_lds(
      (const __attribute__((address_space(1))) void*)(g),
      (__attribute__((address_space(3))) void*)(l), 16, 0, 0);
}

// ---------------------------------------------------------------- convert f32 -> bf16
__global__ __launch_bounds__(256) void cvt3(
    const float* __restrict__ x, const float* __restrict__ wq, const float* __restrict__ wo,
    unsigned short* __restrict__ xb, unsigned short* __restrict__ wqb,
    unsigned short* __restrict__ wob)
{
  const int n1 = 4096 * 1024 / 4, n2 = 3072 * 1024 / 4, n3 = 1024 * 1024 / 4;
  const int total = n1 + n2 + n3;
  for (int t = blockIdx.x * blockDim.x + threadIdx.x; t < total; t += gridDim.x * blockDim.x) {
    const float* s; unsigned short* d; int off;
    if (t < n1)            { s = x;  d = xb;  off = t * 4; }
    else if (t < n1 + n2)  { s = wq; d = wqb; off = (t - n1) * 4; }
    else                   { s = wo; d = wob; off = (t - n1 - n2) * 4; }
    f32x4_t v = *(const f32x4_t*)(s + off);
    us4_t o = { f2bf(v[0]), f2bf(v[1]), f2bf(v[2]), f2bf(v[3]) };
    *(us4_t*)(d + off) = o;
  }
}

// ---------------------------------------------------------------- 128x128 bf16 GEMM, C = A * Bw^T + bias
template<int MODE>
__global__ __launch_bounds__(256) void gemm_bt(
    const unsigned short* __restrict__ A, const unsigned short* __restrict__ Bw,
    const float* __restrict__ bias, float* __restrict__ Cf,
    unsigned short* __restrict__ Qp, unsigned short* __restrict__ Kp,
    unsigned short* __restrict__ Vtp, int M, int N, int K)
{
  __shared__ alignas(16) unsigned short lA[128 * 32];
  __shared__ alignas(16) unsigned short lB[128 * 32];
  const int tid = threadIdx.x, lane = tid & 63, w = tid >> 6;
  const int lo = lane & 15, hi = lane >> 4;
  const int bm = blockIdx.y * 128, bn = blockIdx.x * 128;
  const int wm = (w >> 1) * 64, wn = (w & 1) * 64;

  const f32x4_t zero = {0.f, 0.f, 0.f, 0.f};
  f32x4_t acc[4][4];
#pragma unroll
  for (int i = 0; i < 4; ++i)
#pragma unroll
    for (int j = 0; j < 4; ++j) acc[i][j] = zero;

  const unsigned short* gA[2]; const unsigned short* gB[2];
  unsigned short* lAp[2]; unsigned short* lBp[2];
#pragma unroll
  for (int i = 0; i < 2; ++i) {
    int offb = (i * 4 + w) * 1024;
    int off  = offb + lane * 16;
    int row  = off >> 6;
    int ke   = (off & 63) >> 1;
    gA[i]  = &A [(size_t)(bm + row) * K + ke];
    gB[i]  = &Bw[(size_t)(bn + row) * K + ke];
    lAp[i] = &lA[offb >> 1];
    lBp[i] = &lB[offb >> 1];
  }

  for (int k0 = 0; k0 < K; k0 += 32) {
#pragma unroll
    for (int i = 0; i < 2; ++i) {
      gload_lds16(gA[i] + k0, lAp[i]);
      gload_lds16(gB[i] + k0, lBp[i]);
    }
    __syncthreads();
    short8_t af[4], bb[4];
#pragma unroll
    for (int i = 0; i < 4; ++i) af[i] = *(const short8_t*)&lA[(wm + i * 16 + lo) * 32 + hi * 8];
#pragma unroll
    for (int j = 0; j < 4; ++j) bb[j] = *(const short8_t*)&lB[(wn + j * 16 + lo) * 32 + hi * 8];
#pragma unroll
    for (int i = 0; i < 4; ++i)
#pragma unroll
      for (int j = 0; j < 4; ++j)
        acc[i][j] = __builtin_amdgcn_mfma_f32_16x16x32_bf16(af[i], bb[j], acc[i][j], 0, 0, 0);
    __syncthreads();
  }

#pragma unroll
  for (int i = 0; i < 4; ++i) {
#pragma unroll
    for (int j = 0; j < 4; ++j) {
      int col = bn + wn + j * 16 + lo;
      float bv = bias[col];
#pragma unroll
      for (int r = 0; r < 4; ++r) {
        int row = bm + wm + i * 16 + hi * 4 + r;
        float v = acc[i][j][r] + bv;
        if (MODE == 1) {
          Cf[(size_t)row * N + col] = v;
        } else {
          unsigned short hv = f2bf(v);
          int sec = col >> 10, h = (col >> 6) & 15, d = col & 63;
          int b = row >> 11, ll = row & 2047;
          int bh = b * 16 + h;
          if (sec == 0)      Qp [((size_t)bh * 2048 + ll) * 64 + d] = hv;
          else if (sec == 1) Kp [((size_t)bh * 2048 + ll) * 64 + d] = hv;
          else               Vtp[((size_t)bh * 64 + d) * 2048 + ll] = hv;
        }
      }
    }
  }
}

// ---------------------------------------------------------------- causal flash attention v3
// Q,K: [BH][2048][64] bf16; Vt: [BH][64][2048] bf16; AO: [B][L][1024] bf16
// 4 waves/block, wave owns 16 q-rows, KVBLK=64, pipelined, LPT, defer-max (THR=8).
__global__ __launch_bounds__(256) void attn(
    const unsigned short* __restrict__ Q, const unsigned short* __restrict__ K,
    const unsigned short* __restrict__ V, unsigned short* __restrict__ AO)
{
  const int tid = threadIdx.x, lane = tid & 63, w = tid >> 6;
  const int lo = lane & 15, hi = lane >> 4;
  const int qt = 31 - blockIdx.y;           // LPT: longest q-tiles dispatch first
  const int bh = blockIdx.x;
  const int qbase = qt * 64 + w * 16;
  const unsigned short* Qb = Q + (size_t)bh * 2048 * 64;
  const unsigned short* Kb = K + (size_t)bh * 2048 * 64;
  const unsigned short* Vb = V + (size_t)bh * 64 * 2048;

  __shared__ alignas(16) unsigned short pl[4][16 * 72];  // per-wave P tile, stride 72
  unsigned short* myP = &pl[w][0];

  short8_t qf0 = *(const short8_t*)&Qb[(qbase + lo) * 64 + hi * 8];
  short8_t qf1 = *(const short8_t*)&Qb[(qbase + lo) * 64 + 32 + hi * 8];

  const f32x4_t zero = {0.f, 0.f, 0.f, 0.f};
  f32x4_t o[4] = {zero, zero, zero, zero};
  float m[4] = {-INFINITY, -INFINITY, -INFINITY, -INFINITY};
  float l[4] = {0.f, 0.f, 0.f, 0.f};        // per-lane PARTIAL sums (reduced in epilogue)
  const float SC = 0.125f * LOG2E;          // 1/sqrt(64) * log2(e): exp2 domain
  const float THR = 8.0f;                   // defer-max threshold (P <= 2^8, bf16-safe)

  const int nk = qbase + 16;                // keys needed: k <= qbase+15 (causal)
  const unsigned short* kfb = &Kb[(size_t)lo * 64 + hi * 8];

  short8_t kf[8];
#pragma unroll
  for (int s = 0; s < 4; ++s) {
    kf[s * 2 + 0] = *(const short8_t*)&kfb[(s * 16) * 64];
    kf[s * 2 + 1] = *(const short8_t*)&kfb[(s * 16) * 64 + 32];
  }

  for (int kb = 0; kb < nk; kb += 64) {
    // V loads early: latency hides under QK + softmax
    short8_t vf[8];
#pragma unroll
    for (int j = 0; j < 4; ++j) {
      vf[j * 2 + 0] = *(const short8_t*)&Vb[(size_t)(j * 16 + lo) * 2048 + kb + hi * 8];
      vf[j * 2 + 1] = *(const short8_t*)&Vb[(size_t)(j * 16 + lo) * 2048 + kb + 32 + hi * 8];
    }

    f32x4_t s4[4] = {zero, zero, zero, zero};
    __builtin_amdgcn_s_setprio(1);
#pragma unroll
    for (int s = 0; s < 4; ++s) {
      s4[s] = __builtin_amdgcn_mfma_f32_16x16x32_bf16(qf0, kf[s * 2 + 0], s4[s], 0, 0, 0);
      s4[s] = __builtin_amdgcn_mfma_f32_16x16x32_bf16(qf1, kf[s * 2 + 1], s4[s], 0, 0, 0);
    }
    __builtin_amdgcn_s_setprio(0);

    // prefetch next K tile (hides under softmax+PV)
    if (kb + 64 < nk) {
      const unsigned short* kn = kfb + (size_t)(kb + 64) * 64;
#pragma unroll
      for (int s = 0; s < 4; ++s) {
        kf[s * 2 + 0] = *(const short8_t*)&kn[(s * 16) * 64];
        kf[s * 2 + 1] = *(const short8_t*)&kn[(s * 16) * 64 + 32];
      }
    }

    const bool needmask = (kb + 64 > qbase);
    float a[4][4];   // a[r][s]
    float pm[4];     // per-lane row max (no cross-lane)
#pragma unroll
    for (int r = 0; r < 4; ++r) {
      int q = qbase + hi * 4 + r;
#pragma unroll
      for (int s = 0; s < 4; ++s) {
        float av = s4[s][r] * SC;
        if (needmask && (kb + s * 16 + lo > q)) av = -INFINITY;
        a[r][s] = av;
      }
      pm[r] = fmaxf(fmaxf(a[r][0], a[r][1]), fmaxf(a[r][2], a[r][3]));
    }

    // defer-max: common case skips ALL cross-lane reduction and rescaling (T13)
    bool ok = (pm[0] - m[0] <= THR) && (pm[1] - m[1] <= THR) &&
              (pm[2] - m[2] <= THR) && (pm[3] - m[3] <= THR);
    if (!__all(ok)) {
#pragma unroll
      for (int r = 0; r < 4; ++r) {
        float t = pm[r];
        t = fmaxf(t, __shfl_xor(t, 1));
        t = fmaxf(t, __shfl_xor(t, 2));
        t = fmaxf(t, __shfl_xor(t, 4));
        t = fmaxf(t, __shfl_xor(t, 8));
        float mn = fmaxf(m[r], t);
        float f = __builtin_amdgcn_exp2f(m[r] - mn);
        m[r] = mn;
        l[r] *= f;
#pragma unroll
        for (int j = 0; j < 4; ++j) o[j][r] *= f;
      }
    }

#pragma unroll
    for (int r = 0; r < 4; ++r) {
      float e0 = __builtin_amdgcn_exp2f(a[r][0] - m[r]);
      float e1 = __builtin_amdgcn_exp2f(a[r][1] - m[r]);
      float e2 = __builtin_amdgcn_exp2f(a[r][2] - m[r]);
      float e3 = __builtin_amdgcn_exp2f(a[r][3] - m[r]);
      l[r] += (e0 + e1) + (e2 + e3);
      int prow = (hi * 4 + r) * 72;
      myP[prow + lo]      = f2bf(e0);
      myP[prow + 16 + lo] = f2bf(e1);
      myP[prow + 32 + lo] = f2bf(e2);
      myP[prow + 48 + lo] = f2bf(e3);
    }

    // P re-layout (D-layout -> A-frag) via per-wave LDS; wave-synchronous
    short8_t pf0 = *(const short8_t*)&myP[lo * 72 + hi * 8];
    short8_t pf1 = *(const short8_t*)&myP[lo * 72 + 32 + hi * 8];
    __builtin_amdgcn_s_setprio(1);
#pragma unroll
    for (int j = 0; j < 4; ++j) {
      o[j] = __builtin_amdgcn_mfma_f32_16x16x32_bf16(pf0, vf[j * 2 + 0], o[j], 0, 0, 0);
      o[j] = __builtin_amdgcn_mfma_f32_16x16x32_bf16(pf1, vf[j * 2 + 1], o[j], 0, 0, 0);
    }
    __builtin_amdgcn_s_setprio(0);
  }

  const int b = bh >> 4, h = bh & 15;
#pragma unroll
  for (int r = 0; r < 4; ++r) {
    // deferred l-reduce: once per kernel, butterfly over the 16 lo-lanes
    float ls = l[r];
    ls += __shfl_xor(ls, 1);
    ls += __shfl_xor(ls, 2);
    ls += __shfl_xor(ls, 4);
    ls += __shfl_xor(ls, 8);
    float inv = 1.0f / ls;
    int qrow = qbase + hi * 4 + r;
    size_t base = ((size_t)b * 2048 + qrow) * 1024 + h * 64;
#pragma unroll
    for (int j = 0; j < 4; ++j)
      AO[base + j * 16 + lo] = f2bf(o[j][r] * inv);
  }
}

// ---------------------------------------------------------------- launch
extern "C" void kernel_launch(void* const* d_in, const int* in_sizes, int n_in,
                              void* d_out, int out_size, void* d_ws, size_t ws_size,
                              hipStream_t stream)
{
  (void)in_sizes; (void)n_in; (void)out_size; (void)ws_size;
  const float* x    = (const float*)d_in[0];
  const float* Wqkv = (const float*)d_in[2];
  const float* bqkv = (const float*)d_in[3];
  const float* Wout = (const float*)d_in[4];
  const float* bout = (const float*)d_in[5];

  unsigned short* ws  = (unsigned short*)d_ws;
  unsigned short* xb  = ws;                       // 4096*1024
  unsigned short* wqb = xb  + 4096 * 1024;        // 3072*1024
  unsigned short* wob = wqb + 3072 * 1024;        // 1024*1024
  unsigned short* Qp  = wob + 1024 * 1024;        // 32*2048*64
  unsigned short* Kp  = Qp  + 32 * 2048 * 64;
  unsigned short* Vtp = Kp  + 32 * 2048 * 64;
  unsigned short* AO  = Vtp + 32 * 2048 * 64;     // 4096*1024

  cvt3<<<dim3(2048), dim3(256), 0, stream>>>(x, Wqkv, Wout, xb, wqb, wob);
  gemm_bt<0><<<dim3(24, 32), dim3(256), 0, stream>>>(
      xb, wqb, bqkv, nullptr, Qp, Kp, Vtp, 4096, 3072, 1024);
  attn<<<dim3(32, 32), dim3(256), 0, stream>>>(Qp, Kp, Vtp, AO);
  gemm_bt<1><<<dim3(8, 32), dim3(256), 0, stream>>>(
      AO, wob, bout, (float*)d_out, nullptr, nullptr, nullptr, 4096, 1024, 1024);
}

// Round 6
// 230.989 us; speedup vs baseline: 1.8087x; 1.3762x over previous
//
#include <hip/hip_runtime.h>
#include <hip/hip_bf16.h>

#define LOG2E 1.44269504088896340736f

typedef __attribute__((ext_vector_type(8))) short short8_t;   // 8 bf16 in 4 VGPRs
typedef __attribute__((ext_vector_type(4))) float f32x4_t;
typedef __attribute__((ext_vector_type(4))) unsigned short us4_t;

__device__ __forceinline__ unsigned short f2bf(float f) {
  unsigned u = __builtin_bit_cast(unsigned, f);
  return (unsigned short)((u + 0x7fffu + ((u >> 16) & 1u)) >> 16);
}

__device__ __forceinline__ void gload_lds16(const unsigned short* g, unsigned short* l) {
  __builtin_amdgcn_global_load_lds(
      (const __attribute__((address_space(1))) void*)(g),
      (__attribute__((address_space(3))) void*)(l), 16, 0, 0);
}

// ---------------------------------------------------------------- convert f32 -> bf16
__global__ __launch_bounds__(256) void cvt3(
    const float* __restrict__ x, const float* __restrict__ wq, const float* __restrict__ wo,
    unsigned short* __restrict__ xb, unsigned short* __restrict__ wqb,
    unsigned short* __restrict__ wob)
{
  const int n1 = 4096 * 1024 / 4, n2 = 3072 * 1024 / 4, n3 = 1024 * 1024 / 4;
  const int total = n1 + n2 + n3;
  for (int t = blockIdx.x * blockDim.x + threadIdx.x; t < total; t += gridDim.x * blockDim.x) {
    const float* s; unsigned short* d; int off;
    if (t < n1)            { s = x;  d = xb;  off = t * 4; }
    else if (t < n1 + n2)  { s = wq; d = wqb; off = (t - n1) * 4; }
    else                   { s = wo; d = wob; off = (t - n1 - n2) * 4; }
    f32x4_t v = *(const f32x4_t*)(s + off);
    us4_t o = { f2bf(v[0]), f2bf(v[1]), f2bf(v[2]), f2bf(v[3]) };
    *(us4_t*)(d + off) = o;
  }
}

// ---------------------------------------------------------------- 128x128 bf16 GEMM, C = A * Bw^T + bias
template<int MODE>
__global__ __launch_bounds__(256) void gemm_bt(
    const unsigned short* __restrict__ A, const unsigned short* __restrict__ Bw,
    const float* __restrict__ bias, float* __restrict__ Cf,
    unsigned short* __restrict__ Qp, unsigned short* __restrict__ Kp,
    unsigned short* __restrict__ Vtp, int M, int N, int K)
{
  __shared__ alignas(16) unsigned short lA[128 * 32];
  __shared__ alignas(16) unsigned short lB[128 * 32];
  const int tid = threadIdx.x, lane = tid & 63, w = tid >> 6;
  const int lo = lane & 15, hi = lane >> 4;
  const int bm = blockIdx.y * 128, bn = blockIdx.x * 128;
  const int wm = (w >> 1) * 64, wn = (w & 1) * 64;

  const f32x4_t zero = {0.f, 0.f, 0.f, 0.f};
  f32x4_t acc[4][4];
#pragma unroll
  for (int i = 0; i < 4; ++i)
#pragma unroll
    for (int j = 0; j < 4; ++j) acc[i][j] = zero;

  const unsigned short* gA[2]; const unsigned short* gB[2];
  unsigned short* lAp[2]; unsigned short* lBp[2];
#pragma unroll
  for (int i = 0; i < 2; ++i) {
    int offb = (i * 4 + w) * 1024;
    int off  = offb + lane * 16;
    int row  = off >> 6;
    int ke   = (off & 63) >> 1;
    gA[i]  = &A [(size_t)(bm + row) * K + ke];
    gB[i]  = &Bw[(size_t)(bn + row) * K + ke];
    lAp[i] = &lA[offb >> 1];
    lBp[i] = &lB[offb >> 1];
  }

  for (int k0 = 0; k0 < K; k0 += 32) {
#pragma unroll
    for (int i = 0; i < 2; ++i) {
      gload_lds16(gA[i] + k0, lAp[i]);
      gload_lds16(gB[i] + k0, lBp[i]);
    }
    __syncthreads();
    short8_t af[4], bb[4];
#pragma unroll
    for (int i = 0; i < 4; ++i) af[i] = *(const short8_t*)&lA[(wm + i * 16 + lo) * 32 + hi * 8];
#pragma unroll
    for (int j = 0; j < 4; ++j) bb[j] = *(const short8_t*)&lB[(wn + j * 16 + lo) * 32 + hi * 8];
#pragma unroll
    for (int i = 0; i < 4; ++i)
#pragma unroll
      for (int j = 0; j < 4; ++j)
        acc[i][j] = __builtin_amdgcn_mfma_f32_16x16x32_bf16(af[i], bb[j], acc[i][j], 0, 0, 0);
    __syncthreads();
  }

#pragma unroll
  for (int i = 0; i < 4; ++i) {
#pragma unroll
    for (int j = 0; j < 4; ++j) {
      int col = bn + wn + j * 16 + lo;
      float bv = bias[col];
#pragma unroll
      for (int r = 0; r < 4; ++r) {
        int row = bm + wm + i * 16 + hi * 4 + r;
        float v = acc[i][j][r] + bv;
        if (MODE == 1) {
          Cf[(size_t)row * N + col] = v;
        } else {
          unsigned short hv = f2bf(v);
          int sec = col >> 10, h = (col >> 6) & 15, d = col & 63;
          int b = row >> 11, ll = row & 2047;
          int bh = b * 16 + h;
          if (sec == 0)      Qp [((size_t)bh * 2048 + ll) * 64 + d] = hv;
          else if (sec == 1) Kp [((size_t)bh * 2048 + ll) * 64 + d] = hv;
          else               Vtp[((size_t)bh * 64 + d) * 2048 + ll] = hv;
        }
      }
    }
  }
}

// ---------------------------------------------------------------- causal flash attention v4
// Q,K: [BH][2048][64] bf16; Vt: [BH][64][2048] bf16; AO: [B][L][1024] bf16
// 4 waves/block, wave owns 16 q-rows, KVBLK=64, K/V staged in LDS once per
// block (4x traffic cut), double-buffered via global_load_lds, LPT, defer-max.
// All 4 waves have identical trip count nt = qt+1, so block barriers are safe.
__global__ __launch_bounds__(256) void attn(
    const unsigned short* __restrict__ Q, const unsigned short* __restrict__ K,
    const unsigned short* __restrict__ V, unsigned short* __restrict__ AO)
{
  const int tid = threadIdx.x, lane = tid & 63, w = tid >> 6;
  const int lo = lane & 15, hi = lane >> 4;
  const int qt = 31 - blockIdx.y;           // LPT: longest q-tiles dispatch first
  const int bh = blockIdx.x;
  const int qbase = qt * 64 + w * 16;
  const int nt = qt + 1;                    // 64-key tiles (identical for all waves)
  const unsigned short* Qb = Q + (size_t)bh * 2048 * 64;
  const unsigned short* Kb = K + (size_t)bh * 2048 * 64;
  const unsigned short* Vb = V + (size_t)bh * 64 * 2048;

  // chunk-major tiles: [ck 0..7][row 0..63][8 bf16]; frag reads are 2-way-bank only
  __shared__ alignas(16) unsigned short lK[2][8 * 512];
  __shared__ alignas(16) unsigned short lV[2][8 * 512];
  __shared__ alignas(16) unsigned short pl[4][16 * 72];  // per-wave P tile, stride 72
  unsigned short* myP = &pl[w][0];

  short8_t qf0 = *(const short8_t*)&Qb[(qbase + lo) * 64 + hi * 8];
  short8_t qf1 = *(const short8_t*)&Qb[(qbase + lo) * 64 + 32 + hi * 8];

  const f32x4_t zero = {0.f, 0.f, 0.f, 0.f};
  f32x4_t o[4] = {zero, zero, zero, zero};
  float m[4] = {-INFINITY, -INFINITY, -INFINITY, -INFINITY};
  float l[4] = {0.f, 0.f, 0.f, 0.f};        // per-lane partial sums (reduced at end)
  const float SC = 0.125f * LOG2E;
  const float THR = 8.0f;

  // staging: wave w owns chunks {2w, 2w+1} of both K and V.
  // K chunk c, lane n -> global Kb[(kb+n)*64 + c*8], LDS [(c*64+n)*8]
  // V chunk c, lane n -> global Vb[n*2048 + kb + c*8], LDS [(c*64+n)*8]
  const unsigned short* ksrc = Kb + (size_t)lane * 64 + 2 * w * 8;
  const unsigned short* vsrc = Vb + (size_t)lane * 2048 + 2 * w * 8;
  unsigned short* kd0 = &lK[0][2 * w * 512];
  unsigned short* kd1 = &lK[1][2 * w * 512];
  unsigned short* vd0 = &lV[0][2 * w * 512];
  unsigned short* vd1 = &lV[1][2 * w * 512];

  // prologue: stage tile 0 into buffer 0
  gload_lds16(ksrc,     kd0);
  gload_lds16(ksrc + 8, kd0 + 512);
  gload_lds16(vsrc,     vd0);
  gload_lds16(vsrc + 8, vd0 + 512);

  for (int t = 0; t < nt; ++t) {
    const int kb = t * 64;
    const int cur = t & 1;
    __syncthreads();   // drains vmcnt: tile t ready; prior reads of other buf done

    if (t + 1 < nt) {  // prefetch tile t+1 into the other buffer (drains next barrier)
      const unsigned short* ks = ksrc + (size_t)(kb + 64) * 64;
      const unsigned short* vs = vsrc + (kb + 64);
      unsigned short* kd = cur ? kd0 : kd1;
      unsigned short* vd = cur ? vd0 : vd1;
      gload_lds16(ks,     kd);
      gload_lds16(ks + 8, kd + 512);
      gload_lds16(vs,     vd);
      gload_lds16(vs + 8, vd + 512);
    }
    const unsigned short* lk = cur ? &lK[1][0] : &lK[0][0];
    const unsigned short* lv = cur ? &lV[1][0] : &lV[0][0];

    // QK^T: S[16q][64k], 8 MFMA, K frags from LDS
    f32x4_t s4[4] = {zero, zero, zero, zero};
    __builtin_amdgcn_s_setprio(1);
#pragma unroll
    for (int s = 0; s < 4; ++s) {
      short8_t k0 = *(const short8_t*)&lk[(hi * 64 + s * 16 + lo) * 8];
      short8_t k1 = *(const short8_t*)&lk[((4 + hi) * 64 + s * 16 + lo) * 8];
      s4[s] = __builtin_amdgcn_mfma_f32_16x16x32_bf16(qf0, k0, s4[s], 0, 0, 0);
      s4[s] = __builtin_amdgcn_mfma_f32_16x16x32_bf16(qf1, k1, s4[s], 0, 0, 0);
    }
    __builtin_amdgcn_s_setprio(0);

    const bool needmask = (kb + 64 > qbase);
    float a[4][4];
    float pm[4];
#pragma unroll
    for (int r = 0; r < 4; ++r) {
      int q = qbase + hi * 4 + r;
#pragma unroll
      for (int s = 0; s < 4; ++s) {
        float av = s4[s][r] * SC;
        if (needmask && (kb + s * 16 + lo > q)) av = -INFINITY;
        a[r][s] = av;
      }
      pm[r] = fmaxf(fmaxf(a[r][0], a[r][1]), fmaxf(a[r][2], a[r][3]));
    }

    // defer-max (T13): common path has zero cross-lane work
    bool ok = (pm[0] - m[0] <= THR) && (pm[1] - m[1] <= THR) &&
              (pm[2] - m[2] <= THR) && (pm[3] - m[3] <= THR);
    if (!__all(ok)) {
#pragma unroll
      for (int r = 0; r < 4; ++r) {
        float t2 = pm[r];
        t2 = fmaxf(t2, __shfl_xor(t2, 1));
        t2 = fmaxf(t2, __shfl_xor(t2, 2));
        t2 = fmaxf(t2, __shfl_xor(t2, 4));
        t2 = fmaxf(t2, __shfl_xor(t2, 8));
        float mn = fmaxf(m[r], t2);
        float f = __builtin_amdgcn_exp2f(m[r] - mn);
        m[r] = mn;
        l[r] *= f;
#pragma unroll
        for (int j = 0; j < 4; ++j) o[j][r] *= f;
      }
    }

#pragma unroll
    for (int r = 0; r < 4; ++r) {
      float e0 = __builtin_amdgcn_exp2f(a[r][0] - m[r]);
      float e1 = __builtin_amdgcn_exp2f(a[r][1] - m[r]);
      float e2 = __builtin_amdgcn_exp2f(a[r][2] - m[r]);
      float e3 = __builtin_amdgcn_exp2f(a[r][3] - m[r]);
      l[r] += (e0 + e1) + (e2 + e3);
      int prow = (hi * 4 + r) * 72;
      myP[prow + lo]      = f2bf(e0);
      myP[prow + 16 + lo] = f2bf(e1);
      myP[prow + 32 + lo] = f2bf(e2);
      myP[prow + 48 + lo] = f2bf(e3);
    }

    // P re-layout via per-wave LDS (wave-synchronous), V frags from LDS
    short8_t pf0 = *(const short8_t*)&myP[lo * 72 + hi * 8];
    short8_t pf1 = *(const short8_t*)&myP[lo * 72 + 32 + hi * 8];
    __builtin_amdgcn_s_setprio(1);
#pragma unroll
    for (int j = 0; j < 4; ++j) {
      short8_t v0 = *(const short8_t*)&lv[(hi * 64 + j * 16 + lo) * 8];
      short8_t v1 = *(const short8_t*)&lv[((4 + hi) * 64 + j * 16 + lo) * 8];
      o[j] = __builtin_amdgcn_mfma_f32_16x16x32_bf16(pf0, v0, o[j], 0, 0, 0);
      o[j] = __builtin_amdgcn_mfma_f32_16x16x32_bf16(pf1, v1, o[j], 0, 0, 0);
    }
    __builtin_amdgcn_s_setprio(0);
  }

  const int b = bh >> 4, h = bh & 15;
#pragma unroll
  for (int r = 0; r < 4; ++r) {
    float ls = l[r];
    ls += __shfl_xor(ls, 1);
    ls += __shfl_xor(ls, 2);
    ls += __shfl_xor(ls, 4);
    ls += __shfl_xor(ls, 8);
    float inv = 1.0f / ls;
    int qrow = qbase + hi * 4 + r;
    size_t base = ((size_t)b * 2048 + qrow) * 1024 + h * 64;
#pragma unroll
    for (int j = 0; j < 4; ++j)
      AO[base + j * 16 + lo] = f2bf(o[j][r] * inv);
  }
}

// ---------------------------------------------------------------- launch
extern "C" void kernel_launch(void* const* d_in, const int* in_sizes, int n_in,
                              void* d_out, int out_size, void* d_ws, size_t ws_size,
                              hipStream_t stream)
{
  (void)in_sizes; (void)n_in; (void)out_size; (void)ws_size;
  const float* x    = (const float*)d_in[0];
  const float* Wqkv = (const float*)d_in[2];
  const float* bqkv = (const float*)d_in[3];
  const float* Wout = (const float*)d_in[4];
  const float* bout = (const float*)d_in[5];

  unsigned short* ws  = (unsigned short*)d_ws;
  unsigned short* xb  = ws;                       // 4096*1024
  unsigned short* wqb = xb  + 4096 * 1024;        // 3072*1024
  unsigned short* wob = wqb + 3072 * 1024;        // 1024*1024
  unsigned short* Qp  = wob + 1024 * 1024;        // 32*2048*64
  unsigned short* Kp  = Qp  + 32 * 2048 * 64;
  unsigned short* Vtp = Kp  + 32 * 2048 * 64;
  unsigned short* AO  = Vtp + 32 * 2048 * 64;     // 4096*1024

  cvt3<<<dim3(2048), dim3(256), 0, stream>>>(x, Wqkv, Wout, xb, wqb, wob);
  gemm_bt<0><<<dim3(24, 32), dim3(256), 0, stream>>>(
      xb, wqb, bqkv, nullptr, Qp, Kp, Vtp, 4096, 3072, 1024);
  attn<<<dim3(32, 32), dim3(256), 0, stream>>>(Qp, Kp, Vtp, AO);
  gemm_bt<1><<<dim3(8, 32), dim3(256), 0, stream>>>(
      AO, wob, bout, (float*)d_out, nullptr, nullptr, nullptr, 4096, 1024, 1024);
}